// Round 6
// baseline (51.729 us; speedup 1.0000x reference)
//
#include <hip/hip_runtime.h>
#include <hip/hip_bf16.h>

#define RES 7
#define NCH 256

__device__ __forceinline__ unsigned short f32_to_bf16_rne(float f) {
    unsigned int u = __float_as_uint(f);
    u += 0x7fffu + ((u >> 16) & 1u);
    return (unsigned short)(u >> 16);
}

__device__ __forceinline__ unsigned int pack_bf16x2(float lo, float hi) {
    return (unsigned int)f32_to_bf16_rne(lo) | ((unsigned int)f32_to_bf16_rne(hi) << 16);
}

// ---------------------------------------------------------------------------
// Pass 1 v3: NCHW fp32 -> NHWC bf16. Tile = 64 hw x 256 c, 512 threads.
// Each thread loads a 4hw x 4c block (4x float4), transposes IN REGISTERS,
// stages via 8x ds_write_b64 (was 32x ds_write_b16 @8-way conflict).
// Output: one full 512B row per wave instruction. Persistent grid (832x2).
// ---------------------------------------------------------------------------
__global__ __launch_bounds__(512) void transpose_all_bf16_v3(
    const float* __restrict__ f0, const float* __restrict__ f1,
    const float* __restrict__ f2, const float* __restrict__ f3,
    unsigned short* __restrict__ ws)
{
    __shared__ unsigned short lds[64 * 260];   // [hw][c], 4-ushort row pad

    const int t  = threadIdx.x;
    const int hq = t & 15;      // hw quad within tile
    const int cr = t >> 4;      // 0..31 channel-quad
    const int w  = t >> 6;      // wave 0..7
    const int ln = t & 63;      // lane -> channels 4*ln..4*ln+3 on output

    for (int id = blockIdx.x; id < 1664; id += 832) {
        const int b = (id >= 832) ? 1 : 0;
        const int x = id - (b ? 832 : 0);

        // per-level hw-tile prefix: f0:625, f1:157, f2:40, f3:10 (total 832)
        const int l    = (x >= 625) + (x >= 782) + (x >= 822);
        const int base = (l == 0) ? 0 : (l == 1) ? 625 : (l == 2) ? 782 : 822;
        const int HW   = (l == 0) ? 40000 : (l == 1) ? 10000 : (l == 2) ? 2500 : 625;
        const float* __restrict__ src =
            (l == 0) ? f0 : (l == 1) ? f1 : (l == 2) ? f2 : f3;
        const size_t doff = (l == 0) ? 0u : (l == 1) ? 20480000u
                          : (l == 2) ? 25600000u : 26880000u;

        const int hw0 = (x - base) * 64;
        const float* __restrict__ s    = src + (size_t)b * NCH * HW;
        unsigned short* __restrict__ d = ws + doff + (size_t)b * HW * NCH;
        const int hwq = hw0 + 4 * hq;

#pragma unroll
        for (int g = 0; g < 2; ++g) {
            const int c0 = 4 * cr + 128 * g;
            float va[4][4];                    // [channel i][hw j]
            if (hwq + 3 < HW) {
#pragma unroll
                for (int i = 0; i < 4; ++i) {
                    const float4 f = *(const float4*)(s + (size_t)(c0 + i) * HW + hwq);
                    va[i][0] = f.x; va[i][1] = f.y; va[i][2] = f.z; va[i][3] = f.w;
                }
            } else {
#pragma unroll
                for (int i = 0; i < 4; ++i)
#pragma unroll
                    for (int j = 0; j < 4; ++j)
                        va[i][j] = (hwq + j < HW) ? s[(size_t)(c0 + i) * HW + hwq + j] : 0.0f;
            }
#pragma unroll
            for (int j = 0; j < 4; ++j) {
                uint2 p;
                p.x = pack_bf16x2(va[0][j], va[1][j]);
                p.y = pack_bf16x2(va[2][j], va[3][j]);
                *(uint2*)&lds[(4 * hq + j) * 260 + c0] = p;   // one ds_write_b64
            }
        }
        __syncthreads();

#pragma unroll
        for (int j = 0; j < 8; ++j) {
            const int hwl = w + 8 * j;
            const int hw  = hw0 + hwl;
            if (hw < HW) {
                const uint2 p = *(const uint2*)&lds[hwl * 260 + 4 * ln];
                *(uint2*)(d + (size_t)hw * NCH + 4 * ln) = p;  // 512B/wave contiguous
            }
        }
        __syncthreads();   // LDS reused next tile
    }
}

// ---------------------------------------------------------------------------
// Pass 2: one block per ROI, 512 threads (8 waves).
// Lane = channel-quad (uint2 = 4 bf16); bins strided over 8 groups.
// ---------------------------------------------------------------------------
__global__ __launch_bounds__(512) void roi_gather_nhwc_bf16(
    const unsigned short* __restrict__ ws,
    const float* __restrict__ boxes, const int* __restrict__ bidx,
    float* __restrict__ out)
{
    __shared__ float lds[49 * 260];

    const int r   = blockIdx.x;
    const int t   = threadIdx.x;
    const int cq  = t & 63;
    const int grp = t >> 6;

    const float bx1 = boxes[r * 4 + 0];
    const float by1 = boxes[r * 4 + 1];
    const float bx2 = boxes[r * 4 + 2];
    const float by2 = boxes[r * 4 + 3];

    const float area = fmaxf(bx2 - bx1, 0.0f) * fmaxf(by2 - by1, 0.0f);
    const float s    = sqrtf(area);
    const float lvlf = floorf(4.0f + log2f(s / 224.0f + 1e-6f));
    const int   lvl  = (int)(fminf(fmaxf(lvlf, 2.0f), 5.0f)) - 2;

    float scale; int H; size_t off;
    if      (lvl == 0) { scale = 0.25f;    H = 200; off = 0u; }
    else if (lvl == 1) { scale = 0.125f;   H = 100; off = 20480000u; }
    else if (lvl == 2) { scale = 0.0625f;  H = 50;  off = 25600000u; }
    else               { scale = 0.03125f; H = 25;  off = 26880000u; }
    const int W = H;

    const int b = bidx[r];
    const unsigned short* __restrict__ feat = ws + off + (size_t)b * H * W * NCH;

    const float x1 = bx1 * scale;
    const float y1 = by1 * scale;
    const float roi_w = fmaxf(bx2 * scale - x1, 1.0f);
    const float roi_h = fmaxf(by2 * scale - y1, 1.0f);
    const float bw = roi_w * (1.0f / RES);
    const float bh = roi_h * (1.0f / RES);

    for (int bin = grp; bin < 49; bin += 8) {
        const int py = bin / 7;
        const int px = bin - py * 7;

        float acc0 = 0.0f, acc1 = 0.0f, acc2 = 0.0f, acc3 = 0.0f;
#pragma unroll
        for (int sy = 0; sy < 2; ++sy) {
            const float pyf = (float)py + ((float)sy + 0.5f) * 0.5f;
            const float ysmp = y1 + pyf * bh;
            const bool  vy   = (ysmp >= -1.0f) && (ysmp <= (float)H);
            const float ycl  = fminf(fmaxf(ysmp, 0.0f), (float)(H - 1));
            const int   y0   = (int)floorf(ycl);
            const int   y1i  = min(y0 + 1, H - 1);
            const float ly   = ycl - (float)y0;
            const float hy   = 1.0f - ly;
#pragma unroll
            for (int sx = 0; sx < 2; ++sx) {
                const float pxf = (float)px + ((float)sx + 0.5f) * 0.5f;
                const float xsmp = x1 + pxf * bw;
                const bool  vx   = (xsmp >= -1.0f) && (xsmp <= (float)W);
                const float xcl  = fminf(fmaxf(xsmp, 0.0f), (float)(W - 1));
                const int   x0   = (int)floorf(xcl);
                const int   x1i  = min(x0 + 1, W - 1);
                const float lx   = xcl - (float)x0;
                const float hx   = 1.0f - lx;

                const float m   = (vy && vx) ? 1.0f : 0.0f;
                const float w00 = m * hy * hx;
                const float w01 = m * hy * lx;
                const float w10 = m * ly * hx;
                const float w11 = m * ly * lx;

                const uint2 u00 = *(const uint2*)(feat + ((size_t)(y0  * W + x0 )) * NCH + 4 * cq);
                const uint2 u01 = *(const uint2*)(feat + ((size_t)(y0  * W + x1i)) * NCH + 4 * cq);
                const uint2 u10 = *(const uint2*)(feat + ((size_t)(y1i * W + x0 )) * NCH + 4 * cq);
                const uint2 u11 = *(const uint2*)(feat + ((size_t)(y1i * W + x1i)) * NCH + 4 * cq);

                acc0 += w00 * __uint_as_float(u00.x << 16)
                      + w01 * __uint_as_float(u01.x << 16)
                      + w10 * __uint_as_float(u10.x << 16)
                      + w11 * __uint_as_float(u11.x << 16);
                acc1 += w00 * __uint_as_float(u00.x & 0xffff0000u)
                      + w01 * __uint_as_float(u01.x & 0xffff0000u)
                      + w10 * __uint_as_float(u10.x & 0xffff0000u)
                      + w11 * __uint_as_float(u11.x & 0xffff0000u);
                acc2 += w00 * __uint_as_float(u00.y << 16)
                      + w01 * __uint_as_float(u01.y << 16)
                      + w10 * __uint_as_float(u10.y << 16)
                      + w11 * __uint_as_float(u11.y << 16);
                acc3 += w00 * __uint_as_float(u00.y & 0xffff0000u)
                      + w01 * __uint_as_float(u01.y & 0xffff0000u)
                      + w10 * __uint_as_float(u10.y & 0xffff0000u)
                      + w11 * __uint_as_float(u11.y & 0xffff0000u);
            }
        }
        float4* dst = (float4*)&lds[bin * 260 + 4 * cq];
        *dst = make_float4(acc0 * 0.25f, acc1 * 0.25f, acc2 * 0.25f, acc3 * 0.25f);
    }

    __syncthreads();

    float* __restrict__ o = out + (size_t)r * (NCH * 49);
    for (int i = t; i < NCH * 49; i += 512) {
        const int ch = i / 49;
        const int bn = i - ch * 49;
        o[i] = lds[bn * 260 + ch];
    }
}

// ---------------------------------------------------------------------------
// Fallback (round-1 kernel) if d_ws is too small for the NHWC bf16 copy.
// ---------------------------------------------------------------------------
__global__ __launch_bounds__(256) void roi_align_fpn_kernel(
    const float* __restrict__ f0, const float* __restrict__ f1,
    const float* __restrict__ f2, const float* __restrict__ f3,
    const float* __restrict__ boxes, const int* __restrict__ bidx,
    float* __restrict__ out)
{
    const int r   = blockIdx.x;
    const int bin = blockIdx.y;
    const int c   = threadIdx.x;
    const int py  = bin / RES;
    const int px  = bin - py * RES;

    const float bx1 = boxes[r * 4 + 0];
    const float by1 = boxes[r * 4 + 1];
    const float bx2 = boxes[r * 4 + 2];
    const float by2 = boxes[r * 4 + 3];

    const float area = fmaxf(bx2 - bx1, 0.0f) * fmaxf(by2 - by1, 0.0f);
    const float s    = sqrtf(area);
    const float lvlf = floorf(4.0f + log2f(s / 224.0f + 1e-6f));
    const int   lvl  = (int)(fminf(fmaxf(lvlf, 2.0f), 5.0f)) - 2;

    const float scales[4] = {0.25f, 0.125f, 0.0625f, 0.03125f};
    const int   Hs[4]     = {200, 100, 50, 25};
    const float* feats[4] = {f0, f1, f2, f3};

    const float scale = scales[lvl];
    const int   H     = Hs[lvl];
    const int   W     = H;
    const float* feat = feats[lvl];

    const int b = bidx[r];

    const float x1 = bx1 * scale;
    const float y1 = by1 * scale;
    const float roi_w = fmaxf(bx2 * scale - x1, 1.0f);
    const float roi_h = fmaxf(by2 * scale - y1, 1.0f);
    const float bw = roi_w * (1.0f / RES);
    const float bh = roi_h * (1.0f / RES);

    const float* __restrict__ fc = feat + (size_t)(b * NCH + c) * H * W;

    float acc = 0.0f;
#pragma unroll
    for (int sy = 0; sy < 2; ++sy) {
        const float pyf = (float)py + ((float)sy + 0.5f) * 0.5f;
        const float ys  = y1 + pyf * bh;
        const bool  vy  = (ys >= -1.0f) && (ys <= (float)H);
        const float ycl = fminf(fmaxf(ys, 0.0f), (float)(H - 1));
        const int   y0  = (int)floorf(ycl);
        const int   y1i = min(y0 + 1, H - 1);
        const float ly  = ycl - (float)y0;
        const float hy  = 1.0f - ly;
#pragma unroll
        for (int sx = 0; sx < 2; ++sx) {
            const float pxf = (float)px + ((float)sx + 0.5f) * 0.5f;
            const float xs  = x1 + pxf * bw;
            const bool  vx  = (xs >= -1.0f) && (xs <= (float)W);
            const float xcl = fminf(fmaxf(xs, 0.0f), (float)(W - 1));
            const int   x0  = (int)floorf(xcl);
            const int   x1i = min(x0 + 1, W - 1);
            const float lx  = xcl - (float)x0;
            const float hx  = 1.0f - lx;

            const float v00 = fc[y0  * W + x0 ];
            const float v01 = fc[y0  * W + x1i];
            const float v10 = fc[y1i * W + x0 ];
            const float v11 = fc[y1i * W + x1i];

            const float v = v00 * (hy * hx) + v01 * (hy * lx)
                          + v10 * (ly * hx) + v11 * (ly * lx);
            if (vy && vx) acc += v;
        }
    }

    out[((size_t)r * NCH + c) * (RES * RES) + bin] = acc * 0.25f;
}

extern "C" void kernel_launch(void* const* d_in, const int* in_sizes, int n_in,
                              void* d_out, int out_size, void* d_ws, size_t ws_size,
                              hipStream_t stream)
{
    const float* f0    = (const float*)d_in[0];
    const float* f1    = (const float*)d_in[1];
    const float* f2    = (const float*)d_in[2];
    const float* f3    = (const float*)d_in[3];
    const float* boxes = (const float*)d_in[4];
    const int*   bidx  = (const int*)d_in[5];
    float* out = (float*)d_out;

    const int R = in_sizes[4] / 4;  // 512 boxes

    const size_t need = 27200000ull * sizeof(unsigned short);  // bf16 NHWC copy

    if (ws_size >= need) {
        unsigned short* ws = (unsigned short*)d_ws;
        transpose_all_bf16_v3<<<dim3(832), dim3(512), 0, stream>>>(f0, f1, f2, f3, ws);
        roi_gather_nhwc_bf16<<<dim3(R), dim3(512), 0, stream>>>(ws, boxes, bidx, out);
    } else {
        dim3 grid(R, RES * RES);
        roi_align_fpn_kernel<<<grid, dim3(NCH), 0, stream>>>(f0, f1, f2, f3, boxes, bidx, out);
    }
}

// Round 7
// 49.427 us; speedup vs baseline: 1.0466x; 1.0466x over previous
//
#include <hip/hip_runtime.h>
#include <hip/hip_bf16.h>

#define RES 7
#define NCH 256

__device__ __forceinline__ unsigned short f32_to_bf16_rne(float f) {
    unsigned int u = __float_as_uint(f);
    u += 0x7fffu + ((u >> 16) & 1u);
    return (unsigned short)(u >> 16);
}

__device__ __forceinline__ unsigned int pack_bf16x2(float lo, float hi) {
    return (unsigned int)f32_to_bf16_rne(lo) | ((unsigned int)f32_to_bf16_rne(hi) << 16);
}

// ---------------------------------------------------------------------------
// Pass 1 v4: NCHW fp32 -> NHWC bf16. Tile = 256 hw x 64 c per block.
// KEY: per load instruction a full wave (64 lanes x float4) reads 1KB
// CONTIGUOUS from one channel row (v3 read only 256B/row -> DRAM row thrash).
// Register 4x4 transpose -> ds_write_b64; writes are full 128B line segments.
// Grid: x = hw-tile prefix over levels (210), y = c-tile (4), z = batch (2).
// ---------------------------------------------------------------------------
__global__ __launch_bounds__(512) void transpose_all_bf16_v4(
    const float* __restrict__ f0, const float* __restrict__ f1,
    const float* __restrict__ f2, const float* __restrict__ f3,
    unsigned short* __restrict__ ws)
{
    __shared__ unsigned short lds[256 * 68];   // [hw][64 ch + 4 pad]

    const int xt = blockIdx.x;                 // 0..209
    const int cy = blockIdx.y;                 // 0..3  -> channels 64*cy..
    const int b  = blockIdx.z;

    // per-level hw-tile prefix (256 hw per tile): f0:157, f1:40, f2:10, f3:3
    const int l    = (xt >= 157) + (xt >= 197) + (xt >= 207);
    const int base = (l == 0) ? 0 : (l == 1) ? 157 : (l == 2) ? 197 : 207;
    const int HW   = (l == 0) ? 40000 : (l == 1) ? 10000 : (l == 2) ? 2500 : 625;
    const float* __restrict__ src =
        (l == 0) ? f0 : (l == 1) ? f1 : (l == 2) ? f2 : f3;
    const size_t doff = (l == 0) ? 0u : (l == 1) ? 20480000u
                      : (l == 2) ? 25600000u : 26880000u;

    const int hw0 = (xt - base) * 256;
    const int c0b = 64 * cy;

    const float* __restrict__ s    = src + (size_t)b * NCH * HW;
    unsigned short* __restrict__ d = ws + doff + (size_t)b * HW * NCH;

    const int t   = threadIdx.x;
    const int hq  = t & 63;       // wave-lane -> hw quad (full wave = 256 hw)
    const int cg  = t >> 6;       // wave id 0..7 -> channel group
    const int hwq = hw0 + 4 * hq;

#pragma unroll
    for (int sweep = 0; sweep < 2; ++sweep) {
        const int cl = 4 * (cg + 8 * sweep);   // local channel 0..63
        const int c0 = c0b + cl;
        float va[4][4];                        // [ch i][hw j]
        if (hwq + 3 < HW) {
#pragma unroll
            for (int i = 0; i < 4; ++i) {
                // one wave-instr = 64 lanes x 16B = 1KB contiguous in row c0+i
                const float4 f = *(const float4*)(s + (size_t)(c0 + i) * HW + hwq);
                va[i][0] = f.x; va[i][1] = f.y; va[i][2] = f.z; va[i][3] = f.w;
            }
        } else {
#pragma unroll
            for (int i = 0; i < 4; ++i)
#pragma unroll
                for (int j = 0; j < 4; ++j)
                    va[i][j] = (hwq + j < HW) ? s[(size_t)(c0 + i) * HW + hwq + j] : 0.0f;
        }
#pragma unroll
        for (int j = 0; j < 4; ++j) {
            uint2 p;
            p.x = pack_bf16x2(va[0][j], va[1][j]);
            p.y = pack_bf16x2(va[2][j], va[3][j]);
            *(uint2*)&lds[(4 * hq + j) * 68 + cl] = p;   // ds_write_b64
        }
    }
    __syncthreads();

    // write: 4096 uint2 total; per wave-instr = 4 hw rows x full 128B segment
#pragma unroll
    for (int j = 0; j < 8; ++j) {
        const int idx = t + 512 * j;     // 0..4095
        const int row = idx >> 4;        // local hw 0..255
        const int u   = idx & 15;        // uint2 within 128B row segment
        const int hw  = hw0 + row;
        if (hw < HW) {
            const uint2 p = *(const uint2*)&lds[row * 68 + 4 * u];
            *(uint2*)(d + (size_t)hw * NCH + c0b + 4 * u) = p;
        }
    }
}

// ---------------------------------------------------------------------------
// Pass 2: one block per ROI, 512 threads (8 waves).
// Lane = channel-quad (uint2 = 4 bf16); bins strided over 8 groups.
// ---------------------------------------------------------------------------
__global__ __launch_bounds__(512) void roi_gather_nhwc_bf16(
    const unsigned short* __restrict__ ws,
    const float* __restrict__ boxes, const int* __restrict__ bidx,
    float* __restrict__ out)
{
    __shared__ float lds[49 * 260];

    const int r   = blockIdx.x;
    const int t   = threadIdx.x;
    const int cq  = t & 63;
    const int grp = t >> 6;

    const float bx1 = boxes[r * 4 + 0];
    const float by1 = boxes[r * 4 + 1];
    const float bx2 = boxes[r * 4 + 2];
    const float by2 = boxes[r * 4 + 3];

    const float area = fmaxf(bx2 - bx1, 0.0f) * fmaxf(by2 - by1, 0.0f);
    const float s    = sqrtf(area);
    const float lvlf = floorf(4.0f + log2f(s / 224.0f + 1e-6f));
    const int   lvl  = (int)(fminf(fmaxf(lvlf, 2.0f), 5.0f)) - 2;

    float scale; int H; size_t off;
    if      (lvl == 0) { scale = 0.25f;    H = 200; off = 0u; }
    else if (lvl == 1) { scale = 0.125f;   H = 100; off = 20480000u; }
    else if (lvl == 2) { scale = 0.0625f;  H = 50;  off = 25600000u; }
    else               { scale = 0.03125f; H = 25;  off = 26880000u; }
    const int W = H;

    const int b = bidx[r];
    const unsigned short* __restrict__ feat = ws + off + (size_t)b * H * W * NCH;

    const float x1 = bx1 * scale;
    const float y1 = by1 * scale;
    const float roi_w = fmaxf(bx2 * scale - x1, 1.0f);
    const float roi_h = fmaxf(by2 * scale - y1, 1.0f);
    const float bw = roi_w * (1.0f / RES);
    const float bh = roi_h * (1.0f / RES);

    for (int bin = grp; bin < 49; bin += 8) {
        const int py = bin / 7;
        const int px = bin - py * 7;

        float acc0 = 0.0f, acc1 = 0.0f, acc2 = 0.0f, acc3 = 0.0f;
#pragma unroll
        for (int sy = 0; sy < 2; ++sy) {
            const float pyf = (float)py + ((float)sy + 0.5f) * 0.5f;
            const float ysmp = y1 + pyf * bh;
            const bool  vy   = (ysmp >= -1.0f) && (ysmp <= (float)H);
            const float ycl  = fminf(fmaxf(ysmp, 0.0f), (float)(H - 1));
            const int   y0   = (int)floorf(ycl);
            const int   y1i  = min(y0 + 1, H - 1);
            const float ly   = ycl - (float)y0;
            const float hy   = 1.0f - ly;
#pragma unroll
            for (int sx = 0; sx < 2; ++sx) {
                const float pxf = (float)px + ((float)sx + 0.5f) * 0.5f;
                const float xsmp = x1 + pxf * bw;
                const bool  vx   = (xsmp >= -1.0f) && (xsmp <= (float)W);
                const float xcl  = fminf(fmaxf(xsmp, 0.0f), (float)(W - 1));
                const int   x0   = (int)floorf(xcl);
                const int   x1i  = min(x0 + 1, W - 1);
                const float lx   = xcl - (float)x0;
                const float hx   = 1.0f - lx;

                const float m   = (vy && vx) ? 1.0f : 0.0f;
                const float w00 = m * hy * hx;
                const float w01 = m * hy * lx;
                const float w10 = m * ly * hx;
                const float w11 = m * ly * lx;

                const uint2 u00 = *(const uint2*)(feat + ((size_t)(y0  * W + x0 )) * NCH + 4 * cq);
                const uint2 u01 = *(const uint2*)(feat + ((size_t)(y0  * W + x1i)) * NCH + 4 * cq);
                const uint2 u10 = *(const uint2*)(feat + ((size_t)(y1i * W + x0 )) * NCH + 4 * cq);
                const uint2 u11 = *(const uint2*)(feat + ((size_t)(y1i * W + x1i)) * NCH + 4 * cq);

                acc0 += w00 * __uint_as_float(u00.x << 16)
                      + w01 * __uint_as_float(u01.x << 16)
                      + w10 * __uint_as_float(u10.x << 16)
                      + w11 * __uint_as_float(u11.x << 16);
                acc1 += w00 * __uint_as_float(u00.x & 0xffff0000u)
                      + w01 * __uint_as_float(u01.x & 0xffff0000u)
                      + w10 * __uint_as_float(u10.x & 0xffff0000u)
                      + w11 * __uint_as_float(u11.x & 0xffff0000u);
                acc2 += w00 * __uint_as_float(u00.y << 16)
                      + w01 * __uint_as_float(u01.y << 16)
                      + w10 * __uint_as_float(u10.y << 16)
                      + w11 * __uint_as_float(u11.y << 16);
                acc3 += w00 * __uint_as_float(u00.y & 0xffff0000u)
                      + w01 * __uint_as_float(u01.y & 0xffff0000u)
                      + w10 * __uint_as_float(u10.y & 0xffff0000u)
                      + w11 * __uint_as_float(u11.y & 0xffff0000u);
            }
        }
        float4* dst = (float4*)&lds[bin * 260 + 4 * cq];
        *dst = make_float4(acc0 * 0.25f, acc1 * 0.25f, acc2 * 0.25f, acc3 * 0.25f);
    }

    __syncthreads();

    float* __restrict__ o = out + (size_t)r * (NCH * 49);
    for (int i = t; i < NCH * 49; i += 512) {
        const int ch = i / 49;
        const int bn = i - ch * 49;
        o[i] = lds[bn * 260 + ch];
    }
}

// ---------------------------------------------------------------------------
// Fallback (round-1 kernel) if d_ws is too small for the NHWC bf16 copy.
// ---------------------------------------------------------------------------
__global__ __launch_bounds__(256) void roi_align_fpn_kernel(
    const float* __restrict__ f0, const float* __restrict__ f1,
    const float* __restrict__ f2, const float* __restrict__ f3,
    const float* __restrict__ boxes, const int* __restrict__ bidx,
    float* __restrict__ out)
{
    const int r   = blockIdx.x;
    const int bin = blockIdx.y;
    const int c   = threadIdx.x;
    const int py  = bin / RES;
    const int px  = bin - py * RES;

    const float bx1 = boxes[r * 4 + 0];
    const float by1 = boxes[r * 4 + 1];
    const float bx2 = boxes[r * 4 + 2];
    const float by2 = boxes[r * 4 + 3];

    const float area = fmaxf(bx2 - bx1, 0.0f) * fmaxf(by2 - by1, 0.0f);
    const float s    = sqrtf(area);
    const float lvlf = floorf(4.0f + log2f(s / 224.0f + 1e-6f));
    const int   lvl  = (int)(fminf(fmaxf(lvlf, 2.0f), 5.0f)) - 2;

    const float scales[4] = {0.25f, 0.125f, 0.0625f, 0.03125f};
    const int   Hs[4]     = {200, 100, 50, 25};
    const float* feats[4] = {f0, f1, f2, f3};

    const float scale = scales[lvl];
    const int   H     = Hs[lvl];
    const int   W     = H;
    const float* feat = feats[lvl];

    const int b = bidx[r];

    const float x1 = bx1 * scale;
    const float y1 = by1 * scale;
    const float roi_w = fmaxf(bx2 * scale - x1, 1.0f);
    const float roi_h = fmaxf(by2 * scale - y1, 1.0f);
    const float bw = roi_w * (1.0f / RES);
    const float bh = roi_h * (1.0f / RES);

    const float* __restrict__ fc = feat + (size_t)(b * NCH + c) * H * W;

    float acc = 0.0f;
#pragma unroll
    for (int sy = 0; sy < 2; ++sy) {
        const float pyf = (float)py + ((float)sy + 0.5f) * 0.5f;
        const float ys  = y1 + pyf * bh;
        const bool  vy  = (ys >= -1.0f) && (ys <= (float)H);
        const float ycl = fminf(fmaxf(ys, 0.0f), (float)(H - 1));
        const int   y0  = (int)floorf(ycl);
        const int   y1i = min(y0 + 1, H - 1);
        const float ly  = ycl - (float)y0;
        const float hy  = 1.0f - ly;
#pragma unroll
        for (int sx = 0; sx < 2; ++sx) {
            const float pxf = (float)px + ((float)sx + 0.5f) * 0.5f;
            const float xs  = x1 + pxf * bw;
            const bool  vx  = (xs >= -1.0f) && (xs <= (float)W);
            const float xcl = fminf(fmaxf(xs, 0.0f), (float)(W - 1));
            const int   x0  = (int)floorf(xcl);
            const int   x1i = min(x0 + 1, W - 1);
            const float lx  = xcl - (float)x0;
            const float hx  = 1.0f - lx;

            const float v00 = fc[y0  * W + x0 ];
            const float v01 = fc[y0  * W + x1i];
            const float v10 = fc[y1i * W + x0 ];
            const float v11 = fc[y1i * W + x1i];

            const float v = v00 * (hy * hx) + v01 * (hy * lx)
                          + v10 * (ly * hx) + v11 * (ly * lx);
            if (vy && vx) acc += v;
        }
    }

    out[((size_t)r * NCH + c) * (RES * RES) + bin] = acc * 0.25f;
}

extern "C" void kernel_launch(void* const* d_in, const int* in_sizes, int n_in,
                              void* d_out, int out_size, void* d_ws, size_t ws_size,
                              hipStream_t stream)
{
    const float* f0    = (const float*)d_in[0];
    const float* f1    = (const float*)d_in[1];
    const float* f2    = (const float*)d_in[2];
    const float* f3    = (const float*)d_in[3];
    const float* boxes = (const float*)d_in[4];
    const int*   bidx  = (const int*)d_in[5];
    float* out = (float*)d_out;

    const int R = in_sizes[4] / 4;  // 512 boxes

    const size_t need = 27200000ull * sizeof(unsigned short);  // bf16 NHWC copy

    if (ws_size >= need) {
        unsigned short* ws = (unsigned short*)d_ws;
        transpose_all_bf16_v4<<<dim3(210, 4, 2), dim3(512), 0, stream>>>(f0, f1, f2, f3, ws);
        roi_gather_nhwc_bf16<<<dim3(R), dim3(512), 0, stream>>>(ws, boxes, bidx, out);
    } else {
        dim3 grid(R, RES * RES);
        roi_align_fpn_kernel<<<grid, dim3(NCH), 0, stream>>>(f0, f1, f2, f3, boxes, bidx, out);
    }
}